// Round 5
// baseline (767.608 us; speedup 1.0000x reference)
//
#include <hip/hip_runtime.h>
#include <math.h>

typedef __attribute__((ext_vector_type(8))) short bf16x8;
typedef __attribute__((ext_vector_type(4))) float f32x4;

__device__ __forceinline__ float b2f(unsigned short u) {
    union { unsigned u32; float f; } x; x.u32 = (unsigned)u << 16; return x.f;
}
__device__ __forceinline__ unsigned short f2b(float f) {
    union { float f; unsigned u32; } x; x.f = f;
    unsigned u = x.u32;
    unsigned r = (u + 0x7fffu + ((u >> 16) & 1u)) >> 16;   // RNE
    return (unsigned short)r;
}

__device__ __forceinline__ f32x4 mfma16(bf16x8 a, bf16x8 b, f32x4 c) {
    return __builtin_amdgcn_mfma_f32_16x16x32_bf16(a, b, c, 0, 0, 0);
}

// ---------------- CSR build ----------------

__global__ __launch_bounds__(256) void hist_k(const int* __restrict__ dst, int* __restrict__ deg, int E) {
    int e = blockIdx.x * 256 + threadIdx.x;
    if (e < E) atomicAdd(&deg[dst[e]], 1);
}

__global__ __launch_bounds__(256) void scanA_k(const int* __restrict__ deg, int* __restrict__ rowptr,
                                               int* __restrict__ partials, int N) {
    __shared__ int sh[256];
    int t = threadIdx.x;
    int base = blockIdx.x * 1024 + t * 4;
    int v0 = 0, v1 = 0, v2 = 0, v3 = 0;
    if (base + 0 < N) v0 = deg[base + 0];
    if (base + 1 < N) v1 = deg[base + 1];
    if (base + 2 < N) v2 = deg[base + 2];
    if (base + 3 < N) v3 = deg[base + 3];
    sh[t] = v0 + v1 + v2 + v3;
    __syncthreads();
    for (int off = 1; off < 256; off <<= 1) {
        int add = (t >= off) ? sh[t - off] : 0;
        __syncthreads();
        sh[t] += add;
        __syncthreads();
    }
    int run = (t > 0) ? sh[t - 1] : 0;
    if (base + 0 < N) rowptr[base + 0] = run; run += v0;
    if (base + 1 < N) rowptr[base + 1] = run; run += v1;
    if (base + 2 < N) rowptr[base + 2] = run; run += v2;
    if (base + 3 < N) rowptr[base + 3] = run;
    if (t == 255) partials[blockIdx.x] = sh[255];
}

__global__ void scanB_k(int* partials, int nch) {
    if (threadIdx.x == 0 && blockIdx.x == 0) {
        int run = 0;
        for (int i = 0; i < nch; ++i) { int x = partials[i]; partials[i] = run; run += x; }
        partials[nch] = run;
    }
}

__global__ __launch_bounds__(256) void addoff_k(int* __restrict__ rowptr, const int* __restrict__ partials,
                                                int N, int nch) {
    int t = threadIdx.x;
    int off = partials[blockIdx.x];
    int base = blockIdx.x * 1024;
    for (int i = 0; i < 4; ++i) {
        int idx = base + t + i * 256;
        if (idx < N) rowptr[idx] += off;
    }
    if (blockIdx.x == 0 && t == 0) rowptr[N] = partials[nch];
}

__global__ __launch_bounds__(256) void scatter_k(const int* __restrict__ src, const int* __restrict__ dst,
                                                 const int* __restrict__ rowptr, int* __restrict__ cnt,
                                                 int* __restrict__ srcid, int E) {
    int e = blockIdx.x * 256 + threadIdx.x;
    if (e < E) {
        int d = dst[e];
        int pos = rowptr[d] + atomicAdd(&cnt[d], 1);
        srcid[pos] = src[e];
    }
}

// ---------------- f32 -> bf16 hi/lo split ----------------

__global__ __launch_bounds__(256) void cvt_k(const float* __restrict__ x,
                                             unsigned short* __restrict__ hi,
                                             unsigned short* __restrict__ lo, long n4) {
    long stride = (long)gridDim.x * 256;
    for (long i = (long)blockIdx.x * 256 + threadIdx.x; i < n4; i += stride) {
        float4 v = ((const float4*)x)[i];
        ushort4 h, L;
        h.x = f2b(v.x); L.x = f2b(v.x - b2f(h.x));
        h.y = f2b(v.y); L.y = f2b(v.y - b2f(h.y));
        h.z = f2b(v.z); L.z = f2b(v.z - b2f(h.z));
        h.w = f2b(v.w); L.w = f2b(v.w - b2f(h.w));
        ((ushort4*)hi)[i] = h;
        ((ushort4*)lo)[i] = L;
    }
}

// ---------------- fused Q/K/V/skip projection via bf16 MFMA, split precision ----------------
// X = Xhi + Xlo (bf16 pair), W staged in LDS as hi/lo bf16 fragments.
// acc = Ahi*Bhi + Alo*Bhi + Ahi*Blo  (lo*lo dropped, ~2^-16).
// Block: 256 thr = 4 waves; 128 rows x 112 cols (7 MFMA col-tiles); grid.y=4 covers 448>=416 cols.
// Fragment layouts (16x16x32): A row=lane&15, k=8*(lane>>4)+j; B col=lane&15, same k;
// D col=lane&15, row=4*(lane>>4)+r.

__global__ __launch_bounds__(256) void qkvs_mfma(const unsigned short* __restrict__ Xhi,
    const unsigned short* __restrict__ Xlo, int Cin, int ksteps, int N,
    const float* __restrict__ Wq, const float* __restrict__ bq,
    const float* __restrict__ Wk, const float* __restrict__ bk,
    const float* __restrict__ Wv, const float* __restrict__ bv,
    const float* __restrict__ Ws, const float* __restrict__ bs,
    float* __restrict__ q, unsigned short* __restrict__ kb,
    unsigned short* __restrict__ vb, float* __restrict__ sk)
{
    __shared__ unsigned lds_hi[4 * 7 * 64 * 4];   // [kstep][tile][lane][word] dwords (2 bf16 each)
    __shared__ unsigned lds_lo[4 * 7 * 64 * 4];

    int tid = threadIdx.x;
    int colbase = blockIdx.y * 112;

    // ---- stage W slice into LDS in B-fragment order ----
    int total = ksteps * 7 * 64 * 4;
    for (int idx = tid; idx < total; idx += 256) {
        int word = idx & 3;
        int lane = (idx >> 2) & 63;
        int tmp = idx >> 8;
        int t = tmp % 7, kk = tmp / 7;
        int col = colbase + t * 16 + (lane & 15);
        int k0 = kk * 32 + ((lane >> 4) << 3) + (word << 1);
        float v0 = 0.f, v1 = 0.f;
        if (col < 416) {
            const float* W; int ow, c;
            if (col < 128)      { W = Wq; ow = 128; c = col; }
            else if (col < 256) { W = Wk; ow = 128; c = col - 128; }
            else if (col < 384) { W = Wv; ow = 128; c = col - 256; }
            else                { W = Ws; ow = 32;  c = col - 384; }
            v0 = W[(size_t)k0 * ow + c];
            v1 = W[(size_t)(k0 + 1) * ow + c];
        }
        unsigned short h0 = f2b(v0), h1 = f2b(v1);
        unsigned short l0 = f2b(v0 - b2f(h0)), l1 = f2b(v1 - b2f(h1));
        lds_hi[idx] = (unsigned)h0 | ((unsigned)h1 << 16);
        lds_lo[idx] = (unsigned)l0 | ((unsigned)l1 << 16);
    }
    __syncthreads();

    int lane = tid & 63;
    int wv = tid >> 6;
    int r0 = blockIdx.x * 128 + wv * 32;

    f32x4 acc[2][7];
#pragma unroll
    for (int rt = 0; rt < 2; ++rt)
#pragma unroll
        for (int t = 0; t < 7; ++t) acc[rt][t] = (f32x4){0.f, 0.f, 0.f, 0.f};

    for (int kk = 0; kk < ksteps; ++kk) {
        bf16x8 ah[2], al[2];
#pragma unroll
        for (int rt = 0; rt < 2; ++rt) {
            int row = r0 + rt * 16 + (lane & 15);
            int rowc = row < N ? row : N - 1;
            size_t off = (size_t)rowc * Cin + kk * 32 + ((lane >> 4) << 3);
            ah[rt] = *(const bf16x8*)(Xhi + off);
            al[rt] = *(const bf16x8*)(Xlo + off);
        }
#pragma unroll
        for (int t = 0; t < 7; ++t) {
            bf16x8 bh = *(const bf16x8*)&lds_hi[((kk * 7 + t) * 64 + lane) * 4];
            bf16x8 bl = *(const bf16x8*)&lds_lo[((kk * 7 + t) * 64 + lane) * 4];
#pragma unroll
            for (int rt = 0; rt < 2; ++rt) {
                acc[rt][t] = mfma16(ah[rt], bh, acc[rt][t]);
                acc[rt][t] = mfma16(al[rt], bh, acc[rt][t]);
                acc[rt][t] = mfma16(ah[rt], bl, acc[rt][t]);
            }
        }
    }

    // ---- store with bias; q/sk f32, k/v bf16 ----
#pragma unroll
    for (int t = 0; t < 7; ++t) {
        int col = colbase + t * 16 + (lane & 15);
        if (col >= 416) continue;
        int sel; const float* bp; int c;
        if (col < 128)      { sel = 0; bp = bq; c = col; }
        else if (col < 256) { sel = 1; bp = bk; c = col - 128; }
        else if (col < 384) { sel = 2; bp = bv; c = col - 256; }
        else                { sel = 3; bp = bs; c = col - 384; }
        float bias = bp[c];
#pragma unroll
        for (int rt = 0; rt < 2; ++rt) {
#pragma unroll
            for (int r = 0; r < 4; ++r) {
                int row = r0 + rt * 16 + ((lane >> 4) << 2) + r;
                if (row >= N) continue;
                float val = acc[rt][t][r] + bias;
                if (sel == 0)      q [(size_t)row * 128 + c] = val;
                else if (sel == 1) kb[(size_t)row * 128 + c] = f2b(val);
                else if (sel == 2) vb[(size_t)row * 128 + c] = f2b(val);
                else               sk[(size_t)row * 32  + c] = val;
            }
        }
    }
}

// ---------------- per-node attention over CSR (online softmax) ----------------
// 32 threads per node; k/v gathers are bf16 rows.
// mode 0: write f32 out; mode 1: write bf16 hi/lo pair (feeds next layer's MFMA).

__global__ __launch_bounds__(256) void attn_k(const float* __restrict__ q,
    const unsigned short* __restrict__ k, const unsigned short* __restrict__ v,
    const float* __restrict__ sk,
    const int* __restrict__ rowptr, const int* __restrict__ srcid,
    float* __restrict__ outF, unsigned short* __restrict__ outHi,
    unsigned short* __restrict__ outLo, int mode, int N)
{
    int grp = threadIdx.x >> 5;
    int n = blockIdx.x * 8 + grp;
    if (n >= N) return;
    int l = threadIdx.x & 31;
    int s = l & 7;
    const float scale = 0.17677669529663687f;  // 1/sqrt(32)

    float4 qv = *(const float4*)(q + (size_t)n * 128 + l * 4);
    float4 acc = make_float4(0.f, 0.f, 0.f, 0.f);
    float m = -INFINITY, lsum = 0.f;

    int e0 = rowptr[n], e1 = rowptr[n + 1];
    int sID = (e0 < e1) ? srcid[e0] : 0;
    for (int e = e0; e < e1; ++e) {
        int nextS = (e + 1 < e1) ? srcid[e + 1] : 0;
        ushort4 kraw = *(const ushort4*)(k + (size_t)sID * 128 + l * 4);
        ushort4 vraw = *(const ushort4*)(v + (size_t)sID * 128 + l * 4);
        float p = qv.x * b2f(kraw.x) + qv.y * b2f(kraw.y)
                + qv.z * b2f(kraw.z) + qv.w * b2f(kraw.w);
        p += __shfl_xor(p, 1, 8);
        p += __shfl_xor(p, 2, 8);
        p += __shfl_xor(p, 4, 8);
        float logit = p * scale;
        float mn = fmaxf(m, logit);
        float ex = __expf(logit - mn);
        float sc = __expf(m - mn);
        lsum = lsum * sc + ex;
        acc.x = acc.x * sc + ex * b2f(vraw.x);
        acc.y = acc.y * sc + ex * b2f(vraw.y);
        acc.z = acc.z * sc + ex * b2f(vraw.z);
        acc.w = acc.w * sc + ex * b2f(vraw.w);
        m = mn;
        sID = nextS;
    }

    float inv = 0.25f / fmaxf(lsum, 1e-16f);
    float rx = acc.x * inv, ry = acc.y * inv, rz = acc.z * inv, rw = acc.w * inv;
    rx += __shfl_xor(rx, 8, 32);  rx += __shfl_xor(rx, 16, 32);
    ry += __shfl_xor(ry, 8, 32);  ry += __shfl_xor(ry, 16, 32);
    rz += __shfl_xor(rz, 8, 32);  rz += __shfl_xor(rz, 16, 32);
    rw += __shfl_xor(rw, 8, 32);  rw += __shfl_xor(rw, 16, 32);

    if (l < 8) {
        const float* skp = sk + (size_t)n * 32 + s * 4;
        float o0 = fmaxf(rx + skp[0], 0.f), o1 = fmaxf(ry + skp[1], 0.f);
        float o2 = fmaxf(rz + skp[2], 0.f), o3 = fmaxf(rw + skp[3], 0.f);
        if (mode == 0) {
            *(float4*)(outF + (size_t)n * 32 + s * 4) = make_float4(o0, o1, o2, o3);
        } else {
            ushort4 h, L;
            h.x = f2b(o0); L.x = f2b(o0 - b2f(h.x));
            h.y = f2b(o1); L.y = f2b(o1 - b2f(h.y));
            h.z = f2b(o2); L.z = f2b(o2 - b2f(h.z));
            h.w = f2b(o3); L.w = f2b(o3 - b2f(h.w));
            *(ushort4*)(outHi + (size_t)n * 32 + s * 4) = h;
            *(ushort4*)(outLo + (size_t)n * 32 + s * 4) = L;
        }
    }
}

// ---------------- global mean pool (batch is sorted) ----------------

__global__ __launch_bounds__(256) void pool_k(const float* __restrict__ h, const int* __restrict__ batch,
                                              float* __restrict__ out, int N)
{
    int g = blockIdx.x;
    int t = threadIdx.x;
    int lo = 0, hi = N;
    while (lo < hi) { int mid = (lo + hi) >> 1; if (batch[mid] < g) lo = mid + 1; else hi = mid; }
    int start = lo;
    lo = 0; hi = N;
    while (lo < hi) { int mid = (lo + hi) >> 1; if (batch[mid] < g + 1) lo = mid + 1; else hi = mid; }
    int end = lo;
    int c = t & 31, r0 = t >> 5;
    float s = 0.f;
    for (int r = start + r0; r < end; r += 8) s += h[(size_t)r * 32 + c];
    __shared__ float sh[256];
    sh[t] = s;
    __syncthreads();
    if (t < 32) {
        float tot = sh[t] + sh[t + 32] + sh[t + 64] + sh[t + 96]
                  + sh[t + 128] + sh[t + 160] + sh[t + 192] + sh[t + 224];
        float cnt = (float)(end - start);
        out[(size_t)g * 32 + t] = tot / fmaxf(cnt, 1.f);
    }
}

// ---------------- launch ----------------

extern "C" void kernel_launch(void* const* d_in, const int* in_sizes, int n_in,
                              void* d_out, int out_size, void* d_ws, size_t ws_size,
                              hipStream_t stream) {
    const float* x   = (const float*)d_in[0];
    const int* ei    = (const int*)d_in[1];
    const int* batch = (const int*)d_in[2];
    const float *Wq1 = (const float*)d_in[3],  *bq1 = (const float*)d_in[4];
    const float *Wk1 = (const float*)d_in[5],  *bk1 = (const float*)d_in[6];
    const float *Wv1 = (const float*)d_in[7],  *bv1 = (const float*)d_in[8];
    const float *Ws1 = (const float*)d_in[9],  *bs1 = (const float*)d_in[10];
    const float *Wq2 = (const float*)d_in[11], *bq2 = (const float*)d_in[12];
    const float *Wk2 = (const float*)d_in[13], *bk2 = (const float*)d_in[14];
    const float *Wv2 = (const float*)d_in[15], *bv2 = (const float*)d_in[16];
    const float *Ws2 = (const float*)d_in[17], *bs2 = (const float*)d_in[18];
    float* out = (float*)d_out;

    int N = in_sizes[0] / 128;
    int E = in_sizes[1] / 2;
    const int* src = ei;
    const int* dst = ei + E;

    char* ws = (char*)d_ws;
    size_t off = 0;
    auto alloc = [&](size_t bytes) -> void* {
        void* p = ws + off;
        off += (bytes + 255) & ~(size_t)255;
        return p;
    };
    int* deg      = (int*)alloc((size_t)N * 4);
    int* cnt      = (int*)alloc((size_t)N * 4);
    int* rowptr   = (int*)alloc(((size_t)N + 1) * 4);
    int* partials = (int*)alloc(4096);
    int* srcid    = (int*)alloc((size_t)E * 4);
    unsigned short* Xhi = (unsigned short*)alloc((size_t)N * 128 * 2);
    unsigned short* Xlo = (unsigned short*)alloc((size_t)N * 128 * 2);
    float* q            = (float*)alloc((size_t)N * 128 * 4);
    unsigned short* kb  = (unsigned short*)alloc((size_t)N * 128 * 2);
    unsigned short* vb  = (unsigned short*)alloc((size_t)N * 128 * 2);
    float* sk     = (float*)alloc((size_t)N * 32 * 4);
    unsigned short* h1hi = (unsigned short*)alloc((size_t)N * 32 * 2);
    unsigned short* h1lo = (unsigned short*)alloc((size_t)N * 32 * 2);
    float* h2     = (float*)alloc((size_t)N * 32 * 4);

    hipMemsetAsync(deg, 0, (size_t)N * 4, stream);
    hipMemsetAsync(cnt, 0, (size_t)N * 4, stream);

    int nch = (N + 1023) / 1024;
    hist_k<<<(E + 255) / 256, 256, 0, stream>>>(dst, deg, E);
    scanA_k<<<nch, 256, 0, stream>>>(deg, rowptr, partials, N);
    scanB_k<<<1, 64, 0, stream>>>(partials, nch);
    addoff_k<<<nch, 256, 0, stream>>>(rowptr, partials, N, nch);
    scatter_k<<<(E + 255) / 256, 256, 0, stream>>>(src, dst, rowptr, cnt, srcid, E);

    cvt_k<<<2048, 256, 0, stream>>>(x, Xhi, Xlo, (long)N * 32);

    dim3 gq((N + 127) / 128, 4);
    qkvs_mfma<<<gq, 256, 0, stream>>>(Xhi, Xlo, 128, 4, N,
        Wq1, bq1, Wk1, bk1, Wv1, bv1, Ws1, bs1, q, kb, vb, sk);
    attn_k<<<(N + 7) / 8, 256, 0, stream>>>(q, kb, vb, sk, rowptr, srcid,
        nullptr, h1hi, h1lo, 1, N);
    qkvs_mfma<<<gq, 256, 0, stream>>>(h1hi, h1lo, 32, 1, N,
        Wq2, bq2, Wk2, bk2, Wv2, bv2, Ws2, bs2, q, kb, vb, sk);
    attn_k<<<(N + 7) / 8, 256, 0, stream>>>(q, kb, vb, sk, rowptr, srcid,
        h2, nullptr, nullptr, 0, N);
    pool_k<<<512, 256, 0, stream>>>(h2, batch, out, N);
}

// Round 6
// 652.544 us; speedup vs baseline: 1.1763x; 1.1763x over previous
//
#include <hip/hip_runtime.h>
#include <math.h>

typedef __attribute__((ext_vector_type(8))) short bf16x8;
typedef __attribute__((ext_vector_type(4))) float f32x4;

__device__ __forceinline__ float b2f(unsigned short u) {
    union { unsigned u32; float f; } x; x.u32 = (unsigned)u << 16; return x.f;
}
__device__ __forceinline__ unsigned short f2b(float f) {
    union { float f; unsigned u32; } x; x.f = f;
    unsigned u = x.u32;
    unsigned r = (u + 0x7fffu + ((u >> 16) & 1u)) >> 16;   // RNE
    return (unsigned short)r;
}

__device__ __forceinline__ f32x4 mfma16(bf16x8 a, bf16x8 b, f32x4 c) {
    return __builtin_amdgcn_mfma_f32_16x16x32_bf16(a, b, c, 0, 0, 0);
}

// ---------------- CSR build ----------------

__global__ __launch_bounds__(256) void hist_k(const int* __restrict__ dst, int* __restrict__ deg, int E) {
    int e = blockIdx.x * 256 + threadIdx.x;
    if (e < E) atomicAdd(&deg[dst[e]], 1);
}

__global__ __launch_bounds__(256) void scanA_k(const int* __restrict__ deg, int* __restrict__ rowptr,
                                               int* __restrict__ partials, int N) {
    __shared__ int sh[256];
    int t = threadIdx.x;
    int base = blockIdx.x * 1024 + t * 4;
    int v0 = 0, v1 = 0, v2 = 0, v3 = 0;
    if (base + 0 < N) v0 = deg[base + 0];
    if (base + 1 < N) v1 = deg[base + 1];
    if (base + 2 < N) v2 = deg[base + 2];
    if (base + 3 < N) v3 = deg[base + 3];
    sh[t] = v0 + v1 + v2 + v3;
    __syncthreads();
    for (int off = 1; off < 256; off <<= 1) {
        int add = (t >= off) ? sh[t - off] : 0;
        __syncthreads();
        sh[t] += add;
        __syncthreads();
    }
    int run = (t > 0) ? sh[t - 1] : 0;
    if (base + 0 < N) rowptr[base + 0] = run; run += v0;
    if (base + 1 < N) rowptr[base + 1] = run; run += v1;
    if (base + 2 < N) rowptr[base + 2] = run; run += v2;
    if (base + 3 < N) rowptr[base + 3] = run;
    if (t == 255) partials[blockIdx.x] = sh[255];
}

__global__ void scanB_k(int* partials, int nch) {
    if (threadIdx.x == 0 && blockIdx.x == 0) {
        int run = 0;
        for (int i = 0; i < nch; ++i) { int x = partials[i]; partials[i] = run; run += x; }
        partials[nch] = run;
    }
}

__global__ __launch_bounds__(256) void addoff_k(int* __restrict__ rowptr, const int* __restrict__ partials,
                                                int N, int nch) {
    int t = threadIdx.x;
    int off = partials[blockIdx.x];
    int base = blockIdx.x * 1024;
    for (int i = 0; i < 4; ++i) {
        int idx = base + t + i * 256;
        if (idx < N) rowptr[idx] += off;
    }
    if (blockIdx.x == 0 && t == 0) rowptr[N] = partials[nch];
}

__global__ __launch_bounds__(256) void scatter_k(const int* __restrict__ src, const int* __restrict__ dst,
                                                 const int* __restrict__ rowptr, int* __restrict__ cnt,
                                                 int* __restrict__ srcid, int E) {
    int e = blockIdx.x * 256 + threadIdx.x;
    if (e < E) {
        int d = dst[e];
        int pos = rowptr[d] + atomicAdd(&cnt[d], 1);
        srcid[pos] = src[e];
    }
}

// ---------------- W -> fragment-ordered bf16 hi/lo tables (once per layer) ----------------
// Layout: [tile t (26)][kstep kk][lane (64)][word (4)] dwords, each dword = 2 bf16 (k0,k0+1).
// B-fragment (16x16x32): col = t*16 + (lane&15), k = kk*32 + (lane>>4)*8 + word*2 + {0,1}.

__global__ __launch_bounds__(256) void wprep_k(
    const float* __restrict__ Wq, const float* __restrict__ Wk,
    const float* __restrict__ Wv, const float* __restrict__ Ws,
    int ksteps, unsigned* __restrict__ fhi, unsigned* __restrict__ flo)
{
    int idx = blockIdx.x * 256 + threadIdx.x;
    int total = 26 * ksteps * 64 * 4;
    if (idx >= total) return;
    int w = idx & 3;
    int lane = (idx >> 2) & 63;
    int tmp = idx >> 8;
    int kk = tmp % ksteps;
    int t = tmp / ksteps;
    int col = t * 16 + (lane & 15);
    int k0 = kk * 32 + ((lane >> 4) << 3) + (w << 1);
    const float* W; int ow, c;
    if (col < 128)      { W = Wq; ow = 128; c = col; }
    else if (col < 256) { W = Wk; ow = 128; c = col - 128; }
    else if (col < 384) { W = Wv; ow = 128; c = col - 256; }
    else                { W = Ws; ow = 32;  c = col - 384; }
    float v0 = W[(size_t)k0 * ow + c];
    float v1 = W[(size_t)(k0 + 1) * ow + c];
    unsigned short h0 = f2b(v0), h1 = f2b(v1);
    unsigned short l0 = f2b(v0 - b2f(h0)), l1 = f2b(v1 - b2f(h1));
    fhi[idx] = (unsigned)h0 | ((unsigned)h1 << 16);
    flo[idx] = (unsigned)l0 | ((unsigned)l1 << 16);
}

// ---------------- fused Q/K/V/skip projection via bf16 MFMA, split precision ----------------
// X read as f32, split to hi/lo bf16 in-register. B fragments read from the
// prebuilt L2-resident tables (no LDS). acc = Ahi*Bhi + Alo*Bhi + Ahi*Blo.
// Block: 4 waves, 128 rows; grid.y=4 x 7 col-tiles covers 26 tiles (416 cols).

__global__ __launch_bounds__(256) void qkvs_mfma(const float* __restrict__ X, int Cin, int ksteps, int N,
    const unsigned* __restrict__ fhi, const unsigned* __restrict__ flo,
    const float* __restrict__ bq, const float* __restrict__ bk,
    const float* __restrict__ bv, const float* __restrict__ bs,
    float* __restrict__ q, unsigned short* __restrict__ kb,
    unsigned short* __restrict__ vb, float* __restrict__ sk)
{
    int tid = threadIdx.x;
    int lane = tid & 63, wv = tid >> 6;
    int r0 = blockIdx.x * 128 + wv * 32;
    int tbase = blockIdx.y * 7;
    int ntile = 26 - tbase; if (ntile > 7) ntile = 7;

    f32x4 acc[2][7];
#pragma unroll
    for (int rt = 0; rt < 2; ++rt)
#pragma unroll
        for (int t = 0; t < 7; ++t) acc[rt][t] = (f32x4){0.f, 0.f, 0.f, 0.f};

    for (int kk = 0; kk < ksteps; ++kk) {
        bf16x8 ah[2], al[2];
#pragma unroll
        for (int rt = 0; rt < 2; ++rt) {
            int row = r0 + rt * 16 + (lane & 15);
            int rowc = row < N ? row : N - 1;
            const float* xp = X + (size_t)rowc * Cin + kk * 32 + ((lane >> 4) << 3);
            float4 x0 = *(const float4*)xp;
            float4 x1 = *(const float4*)(xp + 4);
            float xs[8] = {x0.x, x0.y, x0.z, x0.w, x1.x, x1.y, x1.z, x1.w};
#pragma unroll
            for (int j = 0; j < 8; ++j) {
                unsigned short h = f2b(xs[j]);
                unsigned short L = f2b(xs[j] - b2f(h));
                ah[rt][j] = (short)h;
                al[rt][j] = (short)L;
            }
        }
#pragma unroll
        for (int t = 0; t < 7; ++t) {
            if (t < ntile) {
                size_t boff = (size_t)(((tbase + t) * ksteps + kk) * 64 + lane) * 4;
                bf16x8 bh = *(const bf16x8*)&fhi[boff];
                bf16x8 bl = *(const bf16x8*)&flo[boff];
#pragma unroll
                for (int rt = 0; rt < 2; ++rt) {
                    acc[rt][t] = mfma16(ah[rt], bh, acc[rt][t]);
                    acc[rt][t] = mfma16(al[rt], bh, acc[rt][t]);
                    acc[rt][t] = mfma16(ah[rt], bl, acc[rt][t]);
                }
            }
        }
    }

    // ---- store with bias; q/sk f32, k/v bf16 ----
#pragma unroll
    for (int t = 0; t < 7; ++t) {
        int col = (tbase + t) * 16 + (lane & 15);
        if (col >= 416) continue;
        int sel; const float* bp; int c;
        if (col < 128)      { sel = 0; bp = bq; c = col; }
        else if (col < 256) { sel = 1; bp = bk; c = col - 128; }
        else if (col < 384) { sel = 2; bp = bv; c = col - 256; }
        else                { sel = 3; bp = bs; c = col - 384; }
        float bias = bp[c];
#pragma unroll
        for (int rt = 0; rt < 2; ++rt) {
#pragma unroll
            for (int r = 0; r < 4; ++r) {
                int row = r0 + rt * 16 + ((lane >> 4) << 2) + r;
                if (row >= N) continue;
                float val = acc[rt][t][r] + bias;
                if (sel == 0)      q [(size_t)row * 128 + c] = val;
                else if (sel == 1) kb[(size_t)row * 128 + c] = f2b(val);
                else if (sel == 2) vb[(size_t)row * 128 + c] = f2b(val);
                else               sk[(size_t)row * 32  + c] = val;
            }
        }
    }
}

// ---------------- per-node attention over CSR (online softmax) ----------------
// 32 threads per node: lane l holds dims [l*4, l*4+4); k/v gathers are bf16 rows.

__global__ __launch_bounds__(256) void attn_k(const float* __restrict__ q,
    const unsigned short* __restrict__ k, const unsigned short* __restrict__ v,
    const float* __restrict__ sk,
    const int* __restrict__ rowptr, const int* __restrict__ srcid,
    float* __restrict__ out, int N)
{
    int grp = threadIdx.x >> 5;
    int n = blockIdx.x * 8 + grp;
    if (n >= N) return;
    int l = threadIdx.x & 31;
    int s = l & 7;
    const float scale = 0.17677669529663687f;  // 1/sqrt(32)

    float4 qv = *(const float4*)(q + (size_t)n * 128 + l * 4);
    float4 acc = make_float4(0.f, 0.f, 0.f, 0.f);
    float m = -INFINITY, lsum = 0.f;

    int e0 = rowptr[n], e1 = rowptr[n + 1];
    int sID = (e0 < e1) ? srcid[e0] : 0;
    for (int e = e0; e < e1; ++e) {
        int nextS = (e + 1 < e1) ? srcid[e + 1] : 0;
        ushort4 kraw = *(const ushort4*)(k + (size_t)sID * 128 + l * 4);
        ushort4 vraw = *(const ushort4*)(v + (size_t)sID * 128 + l * 4);
        float p = qv.x * b2f(kraw.x) + qv.y * b2f(kraw.y)
                + qv.z * b2f(kraw.z) + qv.w * b2f(kraw.w);
        p += __shfl_xor(p, 1, 8);
        p += __shfl_xor(p, 2, 8);
        p += __shfl_xor(p, 4, 8);
        float logit = p * scale;
        float mn = fmaxf(m, logit);
        float ex = __expf(logit - mn);
        float sc = __expf(m - mn);
        lsum = lsum * sc + ex;
        acc.x = acc.x * sc + ex * b2f(vraw.x);
        acc.y = acc.y * sc + ex * b2f(vraw.y);
        acc.z = acc.z * sc + ex * b2f(vraw.z);
        acc.w = acc.w * sc + ex * b2f(vraw.w);
        m = mn;
        sID = nextS;
    }

    float inv = 0.25f / fmaxf(lsum, 1e-16f);
    float rx = acc.x * inv, ry = acc.y * inv, rz = acc.z * inv, rw = acc.w * inv;
    rx += __shfl_xor(rx, 8, 32);  rx += __shfl_xor(rx, 16, 32);
    ry += __shfl_xor(ry, 8, 32);  ry += __shfl_xor(ry, 16, 32);
    rz += __shfl_xor(rz, 8, 32);  rz += __shfl_xor(rz, 16, 32);
    rw += __shfl_xor(rw, 8, 32);  rw += __shfl_xor(rw, 16, 32);

    if (l < 8) {
        const float* skp = sk + (size_t)n * 32 + s * 4;
        float4 o = make_float4(fmaxf(rx + skp[0], 0.f), fmaxf(ry + skp[1], 0.f),
                               fmaxf(rz + skp[2], 0.f), fmaxf(rw + skp[3], 0.f));
        *(float4*)(out + (size_t)n * 32 + s * 4) = o;
    }
}

// ---------------- global mean pool (batch is sorted) ----------------

__global__ __launch_bounds__(256) void pool_k(const float* __restrict__ h, const int* __restrict__ batch,
                                              float* __restrict__ out, int N)
{
    int g = blockIdx.x;
    int t = threadIdx.x;
    int lo = 0, hi = N;
    while (lo < hi) { int mid = (lo + hi) >> 1; if (batch[mid] < g) lo = mid + 1; else hi = mid; }
    int start = lo;
    lo = 0; hi = N;
    while (lo < hi) { int mid = (lo + hi) >> 1; if (batch[mid] < g + 1) lo = mid + 1; else hi = mid; }
    int end = lo;
    int c = t & 31, r0 = t >> 5;
    float s = 0.f;
    for (int r = start + r0; r < end; r += 8) s += h[(size_t)r * 32 + c];
    __shared__ float sh[256];
    sh[t] = s;
    __syncthreads();
    if (t < 32) {
        float tot = sh[t] + sh[t + 32] + sh[t + 64] + sh[t + 96]
                  + sh[t + 128] + sh[t + 160] + sh[t + 192] + sh[t + 224];
        float cnt = (float)(end - start);
        out[(size_t)g * 32 + t] = tot / fmaxf(cnt, 1.f);
    }
}

// ---------------- launch ----------------

extern "C" void kernel_launch(void* const* d_in, const int* in_sizes, int n_in,
                              void* d_out, int out_size, void* d_ws, size_t ws_size,
                              hipStream_t stream) {
    const float* x   = (const float*)d_in[0];
    const int* ei    = (const int*)d_in[1];
    const int* batch = (const int*)d_in[2];
    const float *Wq1 = (const float*)d_in[3],  *bq1 = (const float*)d_in[4];
    const float *Wk1 = (const float*)d_in[5],  *bk1 = (const float*)d_in[6];
    const float *Wv1 = (const float*)d_in[7],  *bv1 = (const float*)d_in[8];
    const float *Ws1 = (const float*)d_in[9],  *bs1 = (const float*)d_in[10];
    const float *Wq2 = (const float*)d_in[11], *bq2 = (const float*)d_in[12];
    const float *Wk2 = (const float*)d_in[13], *bk2 = (const float*)d_in[14];
    const float *Wv2 = (const float*)d_in[15], *bv2 = (const float*)d_in[16];
    const float *Ws2 = (const float*)d_in[17], *bs2 = (const float*)d_in[18];
    float* out = (float*)d_out;

    int N = in_sizes[0] / 128;
    int E = in_sizes[1] / 2;
    const int* src = ei;
    const int* dst = ei + E;

    char* ws = (char*)d_ws;
    size_t off = 0;
    auto alloc = [&](size_t bytes) -> void* {
        void* p = ws + off;
        off += (bytes + 255) & ~(size_t)255;
        return p;
    };
    int* deg      = (int*)alloc((size_t)N * 4);
    int* cnt      = (int*)alloc((size_t)N * 4);
    int* rowptr   = (int*)alloc(((size_t)N + 1) * 4);
    int* partials = (int*)alloc(4096);
    int* srcid    = (int*)alloc((size_t)E * 4);
    unsigned* fhi1 = (unsigned*)alloc(26 * 4 * 64 * 4 * 4);
    unsigned* flo1 = (unsigned*)alloc(26 * 4 * 64 * 4 * 4);
    unsigned* fhi2 = (unsigned*)alloc(26 * 1 * 64 * 4 * 4);
    unsigned* flo2 = (unsigned*)alloc(26 * 1 * 64 * 4 * 4);
    float* q            = (float*)alloc((size_t)N * 128 * 4);
    unsigned short* kb  = (unsigned short*)alloc((size_t)N * 128 * 2);
    unsigned short* vb  = (unsigned short*)alloc((size_t)N * 128 * 2);
    float* sk     = (float*)alloc((size_t)N * 32 * 4);
    float* h1     = (float*)alloc((size_t)N * 32 * 4);
    float* h2     = (float*)alloc((size_t)N * 32 * 4);

    hipMemsetAsync(deg, 0, (size_t)N * 4, stream);
    hipMemsetAsync(cnt, 0, (size_t)N * 4, stream);

    int nch = (N + 1023) / 1024;
    hist_k<<<(E + 255) / 256, 256, 0, stream>>>(dst, deg, E);
    scanA_k<<<nch, 256, 0, stream>>>(deg, rowptr, partials, N);
    scanB_k<<<1, 64, 0, stream>>>(partials, nch);
    addoff_k<<<nch, 256, 0, stream>>>(rowptr, partials, N, nch);
    scatter_k<<<(E + 255) / 256, 256, 0, stream>>>(src, dst, rowptr, cnt, srcid, E);

    wprep_k<<<(26 * 4 * 64 * 4 + 255) / 256, 256, 0, stream>>>(Wq1, Wk1, Wv1, Ws1, 4, fhi1, flo1);
    wprep_k<<<(26 * 1 * 64 * 4 + 255) / 256, 256, 0, stream>>>(Wq2, Wk2, Wv2, Ws2, 1, fhi2, flo2);

    dim3 gq((N + 127) / 128, 4);
    qkvs_mfma<<<gq, 256, 0, stream>>>(x, 128, 4, N, fhi1, flo1,
        bq1, bk1, bv1, bs1, q, kb, vb, sk);
    attn_k<<<(N + 7) / 8, 256, 0, stream>>>(q, kb, vb, sk, rowptr, srcid, h1, N);
    qkvs_mfma<<<gq, 256, 0, stream>>>(h1, 32, 1, N, fhi2, flo2,
        bq2, bk2, bv2, bs2, q, kb, vb, sk);
    attn_k<<<(N + 7) / 8, 256, 0, stream>>>(q, kb, vb, sk, rowptr, srcid, h2, N);
    pool_k<<<512, 256, 0, stream>>>(h2, batch, out, N);
}

// Round 7
// 636.786 us; speedup vs baseline: 1.2054x; 1.0247x over previous
//
#include <hip/hip_runtime.h>
#include <math.h>

typedef __attribute__((ext_vector_type(8))) short bf16x8;
typedef __attribute__((ext_vector_type(4))) float f32x4;

__device__ __forceinline__ float b2f(unsigned short u) {
    union { unsigned u32; float f; } x; x.u32 = (unsigned)u << 16; return x.f;
}
__device__ __forceinline__ unsigned short f2b(float f) {
    union { float f; unsigned u32; } x; x.f = f;
    unsigned u = x.u32;
    unsigned r = (u + 0x7fffu + ((u >> 16) & 1u)) >> 16;   // RNE
    return (unsigned short)r;
}

__device__ __forceinline__ f32x4 mfma16(bf16x8 a, bf16x8 b, f32x4 c) {
    return __builtin_amdgcn_mfma_f32_16x16x32_bf16(a, b, c, 0, 0, 0);
}

// ---------------- CSR build ----------------

__global__ __launch_bounds__(256) void hist_k(const int* __restrict__ dst, int* __restrict__ deg, int E) {
    int e = blockIdx.x * 256 + threadIdx.x;
    if (e < E) atomicAdd(&deg[dst[e]], 1);
}

__global__ __launch_bounds__(256) void scanA_k(const int* __restrict__ deg, int* __restrict__ rowptr,
                                               int* __restrict__ partials, int N) {
    __shared__ int sh[256];
    int t = threadIdx.x;
    int base = blockIdx.x * 1024 + t * 4;
    int v0 = 0, v1 = 0, v2 = 0, v3 = 0;
    if (base + 0 < N) v0 = deg[base + 0];
    if (base + 1 < N) v1 = deg[base + 1];
    if (base + 2 < N) v2 = deg[base + 2];
    if (base + 3 < N) v3 = deg[base + 3];
    sh[t] = v0 + v1 + v2 + v3;
    __syncthreads();
    for (int off = 1; off < 256; off <<= 1) {
        int add = (t >= off) ? sh[t - off] : 0;
        __syncthreads();
        sh[t] += add;
        __syncthreads();
    }
    int run = (t > 0) ? sh[t - 1] : 0;
    if (base + 0 < N) rowptr[base + 0] = run; run += v0;
    if (base + 1 < N) rowptr[base + 1] = run; run += v1;
    if (base + 2 < N) rowptr[base + 2] = run; run += v2;
    if (base + 3 < N) rowptr[base + 3] = run;
    if (t == 255) partials[blockIdx.x] = sh[255];
}

__global__ void scanB_k(int* partials, int nch) {
    if (threadIdx.x == 0 && blockIdx.x == 0) {
        int run = 0;
        for (int i = 0; i < nch; ++i) { int x = partials[i]; partials[i] = run; run += x; }
        partials[nch] = run;
    }
}

__global__ __launch_bounds__(256) void addoff_k(int* __restrict__ rowptr, const int* __restrict__ partials,
                                                int N, int nch) {
    int t = threadIdx.x;
    int off = partials[blockIdx.x];
    int base = blockIdx.x * 1024;
    for (int i = 0; i < 4; ++i) {
        int idx = base + t + i * 256;
        if (idx < N) rowptr[idx] += off;
    }
    if (blockIdx.x == 0 && t == 0) rowptr[N] = partials[nch];
}

__global__ __launch_bounds__(256) void scatter_k(const int* __restrict__ src, const int* __restrict__ dst,
                                                 const int* __restrict__ rowptr, int* __restrict__ cnt,
                                                 int* __restrict__ srcid, int E) {
    int e = blockIdx.x * 256 + threadIdx.x;
    if (e < E) {
        int d = dst[e];
        int pos = rowptr[d] + atomicAdd(&cnt[d], 1);
        srcid[pos] = src[e];
    }
}

// ---------------- f32 -> bf16 hi/lo split ----------------

__global__ __launch_bounds__(256) void cvt_k(const float* __restrict__ x,
                                             unsigned short* __restrict__ hi,
                                             unsigned short* __restrict__ lo, long n4) {
    long stride = (long)gridDim.x * 256;
    for (long i = (long)blockIdx.x * 256 + threadIdx.x; i < n4; i += stride) {
        float4 v = ((const float4*)x)[i];
        ushort4 h, L;
        h.x = f2b(v.x); L.x = f2b(v.x - b2f(h.x));
        h.y = f2b(v.y); L.y = f2b(v.y - b2f(h.y));
        h.z = f2b(v.z); L.z = f2b(v.z - b2f(h.z));
        h.w = f2b(v.w); L.w = f2b(v.w - b2f(h.w));
        ((ushort4*)hi)[i] = h;
        ((ushort4*)lo)[i] = L;
    }
}

// ---------------- W -> fragment-ordered bf16 hi/lo tables (once per layer) ----------------
// Layout: [tile t (26)][kstep kk][lane (64)][word (4)] dwords, each dword = 2 bf16 (k0,k0+1).
// B-fragment (16x16x32): col = t*16 + (lane&15), k = kk*32 + (lane>>4)*8 + word*2 + {0,1}.

__global__ __launch_bounds__(256) void wprep_k(
    const float* __restrict__ Wq, const float* __restrict__ Wk,
    const float* __restrict__ Wv, const float* __restrict__ Ws,
    int ksteps, unsigned* __restrict__ fhi, unsigned* __restrict__ flo)
{
    int idx = blockIdx.x * 256 + threadIdx.x;
    int total = 26 * ksteps * 64 * 4;
    if (idx >= total) return;
    int w = idx & 3;
    int lane = (idx >> 2) & 63;
    int tmp = idx >> 8;
    int kk = tmp % ksteps;
    int t = tmp / ksteps;
    int col = t * 16 + (lane & 15);
    int k0 = kk * 32 + ((lane >> 4) << 3) + (w << 1);
    const float* W; int ow, c;
    if (col < 128)      { W = Wq; ow = 128; c = col; }
    else if (col < 256) { W = Wk; ow = 128; c = col - 128; }
    else if (col < 384) { W = Wv; ow = 128; c = col - 256; }
    else                { W = Ws; ow = 32;  c = col - 384; }
    float v0 = W[(size_t)k0 * ow + c];
    float v1 = W[(size_t)(k0 + 1) * ow + c];
    unsigned short h0 = f2b(v0), h1 = f2b(v1);
    unsigned short l0 = f2b(v0 - b2f(h0)), l1 = f2b(v1 - b2f(h1));
    fhi[idx] = (unsigned)h0 | ((unsigned)h1 << 16);
    flo[idx] = (unsigned)l0 | ((unsigned)l1 << 16);
}

// ---------------- fused Q/K/V/skip projection via bf16 MFMA, split precision ----------------
// A fragments from precomputed Xhi/Xlo planes (two 16B loads, zero conversion VALU).
// B fragments from prebuilt L2-resident tables (no LDS).
// acc = Ahi*Bhi + Alo*Bhi + Ahi*Blo.
// Block: 4 waves, 128 rows; grid.y=4 x 7 col-tiles covers 26 tiles (416 cols).

__global__ __launch_bounds__(256) void qkvs_mfma(const unsigned short* __restrict__ Xhi,
    const unsigned short* __restrict__ Xlo, int Cin, int ksteps, int N,
    const unsigned* __restrict__ fhi, const unsigned* __restrict__ flo,
    const float* __restrict__ bq, const float* __restrict__ bk,
    const float* __restrict__ bv, const float* __restrict__ bs,
    float* __restrict__ q, unsigned short* __restrict__ kb,
    unsigned short* __restrict__ vb, float* __restrict__ sk)
{
    int tid = threadIdx.x;
    int lane = tid & 63, wv = tid >> 6;
    int r0 = blockIdx.x * 128 + wv * 32;
    int tbase = blockIdx.y * 7;
    int ntile = 26 - tbase; if (ntile > 7) ntile = 7;

    f32x4 acc[2][7];
#pragma unroll
    for (int rt = 0; rt < 2; ++rt)
#pragma unroll
        for (int t = 0; t < 7; ++t) acc[rt][t] = (f32x4){0.f, 0.f, 0.f, 0.f};

    for (int kk = 0; kk < ksteps; ++kk) {
        bf16x8 ah[2], al[2];
#pragma unroll
        for (int rt = 0; rt < 2; ++rt) {
            int row = r0 + rt * 16 + (lane & 15);
            int rowc = row < N ? row : N - 1;
            size_t off = (size_t)rowc * Cin + kk * 32 + ((lane >> 4) << 3);
            ah[rt] = *(const bf16x8*)(Xhi + off);
            al[rt] = *(const bf16x8*)(Xlo + off);
        }
#pragma unroll
        for (int t = 0; t < 7; ++t) {
            if (t < ntile) {
                size_t boff = (size_t)(((tbase + t) * ksteps + kk) * 64 + lane) * 4;
                bf16x8 bh = *(const bf16x8*)&fhi[boff];
                bf16x8 bl = *(const bf16x8*)&flo[boff];
#pragma unroll
                for (int rt = 0; rt < 2; ++rt) {
                    acc[rt][t] = mfma16(ah[rt], bh, acc[rt][t]);
                    acc[rt][t] = mfma16(al[rt], bh, acc[rt][t]);
                    acc[rt][t] = mfma16(ah[rt], bl, acc[rt][t]);
                }
            }
        }
    }

    // ---- store with bias; q/sk f32, k/v bf16 ----
#pragma unroll
    for (int t = 0; t < 7; ++t) {
        int col = (tbase + t) * 16 + (lane & 15);
        if (col >= 416) continue;
        int sel; const float* bp; int c;
        if (col < 128)      { sel = 0; bp = bq; c = col; }
        else if (col < 256) { sel = 1; bp = bk; c = col - 128; }
        else if (col < 384) { sel = 2; bp = bv; c = col - 256; }
        else                { sel = 3; bp = bs; c = col - 384; }
        float bias = bp[c];
#pragma unroll
        for (int rt = 0; rt < 2; ++rt) {
#pragma unroll
            for (int r = 0; r < 4; ++r) {
                int row = r0 + rt * 16 + ((lane >> 4) << 2) + r;
                if (row >= N) continue;
                float val = acc[rt][t][r] + bias;
                if (sel == 0)      q [(size_t)row * 128 + c] = val;
                else if (sel == 1) kb[(size_t)row * 128 + c] = f2b(val);
                else if (sel == 2) vb[(size_t)row * 128 + c] = f2b(val);
                else               sk[(size_t)row * 32  + c] = val;
            }
        }
    }
}

// ---------------- per-node attention over CSR (online softmax) ----------------
// 32 threads per node; k/v gathers are bf16 rows with explicit depth-1 prefetch.
// mode 0: f32 out; mode 1: bf16 hi/lo out (feeds next layer's MFMA A-fragments).

__global__ __launch_bounds__(256) void attn_k(const float* __restrict__ q,
    const unsigned short* __restrict__ k, const unsigned short* __restrict__ v,
    const float* __restrict__ sk,
    const int* __restrict__ rowptr, const int* __restrict__ srcid,
    float* __restrict__ outF, unsigned short* __restrict__ outHi,
    unsigned short* __restrict__ outLo, int mode, int N)
{
    int grp = threadIdx.x >> 5;
    int n = blockIdx.x * 8 + grp;
    if (n >= N) return;
    int l = threadIdx.x & 31;
    int s = l & 7;
    const float scale = 0.17677669529663687f;  // 1/sqrt(32)

    float4 qv = *(const float4*)(q + (size_t)n * 128 + l * 4);
    float4 acc = make_float4(0.f, 0.f, 0.f, 0.f);
    float m = -INFINITY, lsum = 0.f;

    int e0 = rowptr[n], e1 = rowptr[n + 1];
    if (e0 < e1) {
        int sID = srcid[e0];
        ushort4 kcur = *(const ushort4*)(k + (size_t)sID * 128 + l * 4);
        ushort4 vcur = *(const ushort4*)(v + (size_t)sID * 128 + l * 4);
        for (int e = e0; e < e1; ++e) {
            int nextS = (e + 1 < e1) ? srcid[e + 1] : sID;
            // issue next edge's gathers before the serial softmax chain
            ushort4 kn = *(const ushort4*)(k + (size_t)nextS * 128 + l * 4);
            ushort4 vn = *(const ushort4*)(v + (size_t)nextS * 128 + l * 4);
            float p = qv.x * b2f(kcur.x) + qv.y * b2f(kcur.y)
                    + qv.z * b2f(kcur.z) + qv.w * b2f(kcur.w);
            p += __shfl_xor(p, 1, 8);
            p += __shfl_xor(p, 2, 8);
            p += __shfl_xor(p, 4, 8);
            float logit = p * scale;
            float mn = fmaxf(m, logit);
            float ex = __expf(logit - mn);
            float sc = __expf(m - mn);
            lsum = lsum * sc + ex;
            acc.x = acc.x * sc + ex * b2f(vcur.x);
            acc.y = acc.y * sc + ex * b2f(vcur.y);
            acc.z = acc.z * sc + ex * b2f(vcur.z);
            acc.w = acc.w * sc + ex * b2f(vcur.w);
            m = mn;
            kcur = kn; vcur = vn;
        }
    }

    float inv = 0.25f / fmaxf(lsum, 1e-16f);
    float rx = acc.x * inv, ry = acc.y * inv, rz = acc.z * inv, rw = acc.w * inv;
    rx += __shfl_xor(rx, 8, 32);  rx += __shfl_xor(rx, 16, 32);
    ry += __shfl_xor(ry, 8, 32);  ry += __shfl_xor(ry, 16, 32);
    rz += __shfl_xor(rz, 8, 32);  rz += __shfl_xor(rz, 16, 32);
    rw += __shfl_xor(rw, 8, 32);  rw += __shfl_xor(rw, 16, 32);

    if (l < 8) {
        const float* skp = sk + (size_t)n * 32 + s * 4;
        float o0 = fmaxf(rx + skp[0], 0.f), o1 = fmaxf(ry + skp[1], 0.f);
        float o2 = fmaxf(rz + skp[2], 0.f), o3 = fmaxf(rw + skp[3], 0.f);
        if (mode == 0) {
            *(float4*)(outF + (size_t)n * 32 + s * 4) = make_float4(o0, o1, o2, o3);
        } else {
            ushort4 h, L;
            h.x = f2b(o0); L.x = f2b(o0 - b2f(h.x));
            h.y = f2b(o1); L.y = f2b(o1 - b2f(h.y));
            h.z = f2b(o2); L.z = f2b(o2 - b2f(h.z));
            h.w = f2b(o3); L.w = f2b(o3 - b2f(h.w));
            *(ushort4*)(outHi + (size_t)n * 32 + s * 4) = h;
            *(ushort4*)(outLo + (size_t)n * 32 + s * 4) = L;
        }
    }
}

// ---------------- global mean pool (batch is sorted) ----------------

__global__ __launch_bounds__(256) void pool_k(const float* __restrict__ h, const int* __restrict__ batch,
                                              float* __restrict__ out, int N)
{
    int g = blockIdx.x;
    int t = threadIdx.x;
    int lo = 0, hi = N;
    while (lo < hi) { int mid = (lo + hi) >> 1; if (batch[mid] < g) lo = mid + 1; else hi = mid; }
    int start = lo;
    lo = 0; hi = N;
    while (lo < hi) { int mid = (lo + hi) >> 1; if (batch[mid] < g + 1) lo = mid + 1; else hi = mid; }
    int end = lo;
    int c = t & 31, r0 = t >> 5;
    float s = 0.f;
    for (int r = start + r0; r < end; r += 8) s += h[(size_t)r * 32 + c];
    __shared__ float sh[256];
    sh[t] = s;
    __syncthreads();
    if (t < 32) {
        float tot = sh[t] + sh[t + 32] + sh[t + 64] + sh[t + 96]
                  + sh[t + 128] + sh[t + 160] + sh[t + 192] + sh[t + 224];
        float cnt = (float)(end - start);
        out[(size_t)g * 32 + t] = tot / fmaxf(cnt, 1.f);
    }
}

// ---------------- launch ----------------

extern "C" void kernel_launch(void* const* d_in, const int* in_sizes, int n_in,
                              void* d_out, int out_size, void* d_ws, size_t ws_size,
                              hipStream_t stream) {
    const float* x   = (const float*)d_in[0];
    const int* ei    = (const int*)d_in[1];
    const int* batch = (const int*)d_in[2];
    const float *Wq1 = (const float*)d_in[3],  *bq1 = (const float*)d_in[4];
    const float *Wk1 = (const float*)d_in[5],  *bk1 = (const float*)d_in[6];
    const float *Wv1 = (const float*)d_in[7],  *bv1 = (const float*)d_in[8];
    const float *Ws1 = (const float*)d_in[9],  *bs1 = (const float*)d_in[10];
    const float *Wq2 = (const float*)d_in[11], *bq2 = (const float*)d_in[12];
    const float *Wk2 = (const float*)d_in[13], *bk2 = (const float*)d_in[14];
    const float *Wv2 = (const float*)d_in[15], *bv2 = (const float*)d_in[16];
    const float *Ws2 = (const float*)d_in[17], *bs2 = (const float*)d_in[18];
    float* out = (float*)d_out;

    int N = in_sizes[0] / 128;
    int E = in_sizes[1] / 2;
    const int* src = ei;
    const int* dst = ei + E;

    char* ws = (char*)d_ws;
    size_t off = 0;
    auto alloc = [&](size_t bytes) -> void* {
        void* p = ws + off;
        off += (bytes + 255) & ~(size_t)255;
        return p;
    };
    int* deg      = (int*)alloc((size_t)N * 4);
    int* cnt      = (int*)alloc((size_t)N * 4);
    int* rowptr   = (int*)alloc(((size_t)N + 1) * 4);
    int* partials = (int*)alloc(4096);
    int* srcid    = (int*)alloc((size_t)E * 4);
    unsigned* fhi1 = (unsigned*)alloc(26 * 4 * 64 * 4 * 4);
    unsigned* flo1 = (unsigned*)alloc(26 * 4 * 64 * 4 * 4);
    unsigned* fhi2 = (unsigned*)alloc(26 * 1 * 64 * 4 * 4);
    unsigned* flo2 = (unsigned*)alloc(26 * 1 * 64 * 4 * 4);
    unsigned short* Xhi = (unsigned short*)alloc((size_t)N * 128 * 2);
    unsigned short* Xlo = (unsigned short*)alloc((size_t)N * 128 * 2);
    float* q            = (float*)alloc((size_t)N * 128 * 4);
    unsigned short* kb  = (unsigned short*)alloc((size_t)N * 128 * 2);
    unsigned short* vb  = (unsigned short*)alloc((size_t)N * 128 * 2);
    float* sk     = (float*)alloc((size_t)N * 32 * 4);
    unsigned short* h1hi = (unsigned short*)alloc((size_t)N * 32 * 2);
    unsigned short* h1lo = (unsigned short*)alloc((size_t)N * 32 * 2);
    float* h2     = (float*)alloc((size_t)N * 32 * 4);

    hipMemsetAsync(deg, 0, (size_t)N * 4, stream);
    hipMemsetAsync(cnt, 0, (size_t)N * 4, stream);

    int nch = (N + 1023) / 1024;
    hist_k<<<(E + 255) / 256, 256, 0, stream>>>(dst, deg, E);
    scanA_k<<<nch, 256, 0, stream>>>(deg, rowptr, partials, N);
    scanB_k<<<1, 64, 0, stream>>>(partials, nch);
    addoff_k<<<nch, 256, 0, stream>>>(rowptr, partials, N, nch);
    scatter_k<<<(E + 255) / 256, 256, 0, stream>>>(src, dst, rowptr, cnt, srcid, E);

    wprep_k<<<(26 * 4 * 64 * 4 + 255) / 256, 256, 0, stream>>>(Wq1, Wk1, Wv1, Ws1, 4, fhi1, flo1);
    wprep_k<<<(26 * 1 * 64 * 4 + 255) / 256, 256, 0, stream>>>(Wq2, Wk2, Wv2, Ws2, 1, fhi2, flo2);
    cvt_k<<<2048, 256, 0, stream>>>(x, Xhi, Xlo, (long)N * 32);

    dim3 gq((N + 127) / 128, 4);
    qkvs_mfma<<<gq, 256, 0, stream>>>(Xhi, Xlo, 128, 4, N, fhi1, flo1,
        bq1, bk1, bv1, bs1, q, kb, vb, sk);
    attn_k<<<(N + 7) / 8, 256, 0, stream>>>(q, kb, vb, sk, rowptr, srcid,
        nullptr, h1hi, h1lo, 1, N);
    qkvs_mfma<<<gq, 256, 0, stream>>>(h1hi, h1lo, 32, 1, N, fhi2, flo2,
        bq2, bk2, bv2, bs2, q, kb, vb, sk);
    attn_k<<<(N + 7) / 8, 256, 0, stream>>>(q, kb, vb, sk, rowptr, srcid,
        h2, nullptr, nullptr, 0, N);
    pool_k<<<512, 256, 0, stream>>>(h2, batch, out, N);
}

// Round 8
// 587.132 us; speedup vs baseline: 1.3074x; 1.0846x over previous
//
#include <hip/hip_runtime.h>
#include <math.h>

typedef __attribute__((ext_vector_type(8))) short bf16x8;
typedef __attribute__((ext_vector_type(4))) float f32x4;

__device__ __forceinline__ float b2f(unsigned short u) {
    union { unsigned u32; float f; } x; x.u32 = (unsigned)u << 16; return x.f;
}
__device__ __forceinline__ unsigned short f2b(float f) {
    union { float f; unsigned u32; } x; x.f = f;
    unsigned u = x.u32;
    unsigned r = (u + 0x7fffu + ((u >> 16) & 1u)) >> 16;   // RNE
    return (unsigned short)r;
}

__device__ __forceinline__ f32x4 mfma16(bf16x8 a, bf16x8 b, f32x4 c) {
    return __builtin_amdgcn_mfma_f32_16x16x32_bf16(a, b, c, 0, 0, 0);
}

// ---------------- CSR build ----------------

__global__ __launch_bounds__(256) void hist_k(const int* __restrict__ dst, int* __restrict__ deg, int E) {
    int e = blockIdx.x * 256 + threadIdx.x;
    if (e < E) atomicAdd(&deg[dst[e]], 1);
}

__global__ __launch_bounds__(256) void scanA_k(const int* __restrict__ deg, int* __restrict__ rowptr,
                                               int* __restrict__ partials, int N) {
    __shared__ int sh[256];
    int t = threadIdx.x;
    int base = blockIdx.x * 1024 + t * 4;
    int v0 = 0, v1 = 0, v2 = 0, v3 = 0;
    if (base + 0 < N) v0 = deg[base + 0];
    if (base + 1 < N) v1 = deg[base + 1];
    if (base + 2 < N) v2 = deg[base + 2];
    if (base + 3 < N) v3 = deg[base + 3];
    sh[t] = v0 + v1 + v2 + v3;
    __syncthreads();
    for (int off = 1; off < 256; off <<= 1) {
        int add = (t >= off) ? sh[t - off] : 0;
        __syncthreads();
        sh[t] += add;
        __syncthreads();
    }
    int run = (t > 0) ? sh[t - 1] : 0;
    if (base + 0 < N) rowptr[base + 0] = run; run += v0;
    if (base + 1 < N) rowptr[base + 1] = run; run += v1;
    if (base + 2 < N) rowptr[base + 2] = run; run += v2;
    if (base + 3 < N) rowptr[base + 3] = run;
    if (t == 255) partials[blockIdx.x] = sh[255];
}

__global__ void scanB_k(int* partials, int nch) {
    if (threadIdx.x == 0 && blockIdx.x == 0) {
        int run = 0;
        for (int i = 0; i < nch; ++i) { int x = partials[i]; partials[i] = run; run += x; }
        partials[nch] = run;
    }
}

__global__ __launch_bounds__(256) void addoff_k(int* __restrict__ rowptr, const int* __restrict__ partials,
                                                int N, int nch) {
    int t = threadIdx.x;
    int off = partials[blockIdx.x];
    int base = blockIdx.x * 1024;
    for (int i = 0; i < 4; ++i) {
        int idx = base + t + i * 256;
        if (idx < N) rowptr[idx] += off;
    }
    if (blockIdx.x == 0 && t == 0) rowptr[N] = partials[nch];
}

__global__ __launch_bounds__(256) void scatter_k(const int* __restrict__ src, const int* __restrict__ dst,
                                                 const int* __restrict__ rowptr, int* __restrict__ cnt,
                                                 int* __restrict__ srcid, int E) {
    int e = blockIdx.x * 256 + threadIdx.x;
    if (e < E) {
        int d = dst[e];
        int pos = rowptr[d] + atomicAdd(&cnt[d], 1);
        srcid[pos] = src[e];
    }
}

// ---------------- f32 -> bf16 hi/lo split ----------------

__global__ __launch_bounds__(256) void cvt_k(const float* __restrict__ x,
                                             unsigned short* __restrict__ hi,
                                             unsigned short* __restrict__ lo, long n4) {
    long stride = (long)gridDim.x * 256;
    for (long i = (long)blockIdx.x * 256 + threadIdx.x; i < n4; i += stride) {
        float4 v = ((const float4*)x)[i];
        ushort4 h, L;
        h.x = f2b(v.x); L.x = f2b(v.x - b2f(h.x));
        h.y = f2b(v.y); L.y = f2b(v.y - b2f(h.y));
        h.z = f2b(v.z); L.z = f2b(v.z - b2f(h.z));
        h.w = f2b(v.w); L.w = f2b(v.w - b2f(h.w));
        ((ushort4*)hi)[i] = h;
        ((ushort4*)lo)[i] = L;
    }
}

// ---------------- W -> fragment-ordered bf16 hi/lo tables (once per layer) ----------------
// Layout: [tile t (26)][kstep kk][lane (64)][word (4)] dwords, each dword = 2 bf16 (k0,k0+1).
// B-fragment (16x16x32): col = t*16 + (lane&15), k = kk*32 + (lane>>4)*8 + word*2 + {0,1}.

__global__ __launch_bounds__(256) void wprep_k(
    const float* __restrict__ Wq, const float* __restrict__ Wk,
    const float* __restrict__ Wv, const float* __restrict__ Ws,
    int ksteps, unsigned* __restrict__ fhi, unsigned* __restrict__ flo)
{
    int idx = blockIdx.x * 256 + threadIdx.x;
    int total = 26 * ksteps * 64 * 4;
    if (idx >= total) return;
    int w = idx & 3;
    int lane = (idx >> 2) & 63;
    int tmp = idx >> 8;
    int kk = tmp % ksteps;
    int t = tmp / ksteps;
    int col = t * 16 + (lane & 15);
    int k0 = kk * 32 + ((lane >> 4) << 3) + (w << 1);
    const float* W; int ow, c;
    if (col < 128)      { W = Wq; ow = 128; c = col; }
    else if (col < 256) { W = Wk; ow = 128; c = col - 128; }
    else if (col < 384) { W = Wv; ow = 128; c = col - 256; }
    else                { W = Ws; ow = 32;  c = col - 384; }
    float v0 = W[(size_t)k0 * ow + c];
    float v1 = W[(size_t)(k0 + 1) * ow + c];
    unsigned short h0 = f2b(v0), h1 = f2b(v1);
    unsigned short l0 = f2b(v0 - b2f(h0)), l1 = f2b(v1 - b2f(h1));
    fhi[idx] = (unsigned)h0 | ((unsigned)h1 << 16);
    flo[idx] = (unsigned)l0 | ((unsigned)l1 << 16);
}

// ---------------- fused Q/K/V/skip projection via bf16 MFMA, split precision ----------------
// A fragments from precomputed Xhi/Xlo planes (16B loads). B fragments staged in LDS
// from the prebuilt fragment-ordered tables (coalesced float4 fill, CHUNK ksteps at a
// time -> 28KB max -> 5 blocks/CU), read back via conflict-free ds_read_b128.
// acc = Ahi*Bhi + Alo*Bhi + Ahi*Blo.

template<int KSTEPS, int CHUNK>
__global__ __launch_bounds__(256) void qkvs_mfma(const unsigned short* __restrict__ Xhi,
    const unsigned short* __restrict__ Xlo, int Cin, int N,
    const unsigned* __restrict__ fhi, const unsigned* __restrict__ flo,
    const float* __restrict__ bq, const float* __restrict__ bk,
    const float* __restrict__ bv, const float* __restrict__ bs,
    float* __restrict__ q, unsigned short* __restrict__ kb,
    unsigned short* __restrict__ vb, float* __restrict__ sk)
{
    constexpr int NIDX = CHUNK * 7 * 64;            // float4 units per plane
    __shared__ float4 ldsB[2 * NIDX];               // [plane][kk_local][tile][lane]

    int tid = threadIdx.x;
    int lane = tid & 63, wv = tid >> 6;
    int r0 = blockIdx.x * 128 + wv * 32;
    int tbase = blockIdx.y * 7;
    int ntile = 26 - tbase; if (ntile > 7) ntile = 7;

    f32x4 acc[2][7];
#pragma unroll
    for (int rt = 0; rt < 2; ++rt)
#pragma unroll
        for (int t = 0; t < 7; ++t) acc[rt][t] = (f32x4){0.f, 0.f, 0.f, 0.f};

    constexpr int NPASS = KSTEPS / CHUNK;
#pragma unroll
    for (int pass = 0; pass < NPASS; ++pass) {
        int kbase = pass * CHUNK;
        if (pass) __syncthreads();                  // previous pass done reading LDS
        // ---- coalesced LDS fill from fragment tables ----
        for (int idx = tid; idx < NIDX; idx += 256) {
            int l = idx & 63;
            int tt = (idx >> 6) % 7;
            int kkl = (idx >> 6) / 7;
            if (tbase + tt < 26) {
                size_t src = ((size_t)((tbase + tt) * KSTEPS + kbase + kkl) * 64 + l);
                ldsB[idx]        = *(const float4*)&fhi[src * 4];
                ldsB[NIDX + idx] = *(const float4*)&flo[src * 4];
            }
        }
        __syncthreads();

#pragma unroll
        for (int kkl = 0; kkl < CHUNK; ++kkl) {
            int kk = kbase + kkl;
            bf16x8 ah[2], al[2];
#pragma unroll
            for (int rt = 0; rt < 2; ++rt) {
                int row = r0 + rt * 16 + (lane & 15);
                int rowc = row < N ? row : N - 1;
                size_t off = (size_t)rowc * Cin + kk * 32 + ((lane >> 4) << 3);
                ah[rt] = *(const bf16x8*)(Xhi + off);
                al[rt] = *(const bf16x8*)(Xlo + off);
            }
#pragma unroll
            for (int t = 0; t < 7; ++t) {
                if (t < ntile) {
                    int bi = (kkl * 7 + t) * 64 + lane;
                    bf16x8 bh = *(const bf16x8*)&ldsB[bi];
                    bf16x8 bl = *(const bf16x8*)&ldsB[NIDX + bi];
#pragma unroll
                    for (int rt = 0; rt < 2; ++rt) {
                        acc[rt][t] = mfma16(ah[rt], bh, acc[rt][t]);
                        acc[rt][t] = mfma16(al[rt], bh, acc[rt][t]);
                        acc[rt][t] = mfma16(ah[rt], bl, acc[rt][t]);
                    }
                }
            }
        }
    }

    // ---- store with bias; q/sk f32, k/v bf16 ----
#pragma unroll
    for (int t = 0; t < 7; ++t) {
        int col = (tbase + t) * 16 + (lane & 15);
        if (col >= 416) continue;
        int sel; const float* bp; int c;
        if (col < 128)      { sel = 0; bp = bq; c = col; }
        else if (col < 256) { sel = 1; bp = bk; c = col - 128; }
        else if (col < 384) { sel = 2; bp = bv; c = col - 256; }
        else                { sel = 3; bp = bs; c = col - 384; }
        float bias = bp[c];
#pragma unroll
        for (int rt = 0; rt < 2; ++rt) {
#pragma unroll
            for (int r = 0; r < 4; ++r) {
                int row = r0 + rt * 16 + ((lane >> 4) << 2) + r;
                if (row >= N) continue;
                float val = acc[rt][t][r] + bias;
                if (sel == 0)      q [(size_t)row * 128 + c] = val;
                else if (sel == 1) kb[(size_t)row * 128 + c] = f2b(val);
                else if (sel == 2) vb[(size_t)row * 128 + c] = f2b(val);
                else               sk[(size_t)row * 32  + c] = val;
            }
        }
    }
}

// ---------------- per-node attention over CSR (online softmax) ----------------
// 32 threads per node; k/v gathers are bf16 rows with explicit depth-1 prefetch.
// mode 0: f32 out; mode 1: bf16 hi/lo out (feeds next layer's MFMA A-fragments).

__global__ __launch_bounds__(256) void attn_k(const float* __restrict__ q,
    const unsigned short* __restrict__ k, const unsigned short* __restrict__ v,
    const float* __restrict__ sk,
    const int* __restrict__ rowptr, const int* __restrict__ srcid,
    float* __restrict__ outF, unsigned short* __restrict__ outHi,
    unsigned short* __restrict__ outLo, int mode, int N)
{
    int grp = threadIdx.x >> 5;
    int n = blockIdx.x * 8 + grp;
    if (n >= N) return;
    int l = threadIdx.x & 31;
    int s = l & 7;
    const float scale = 0.17677669529663687f;  // 1/sqrt(32)

    float4 qv = *(const float4*)(q + (size_t)n * 128 + l * 4);
    float4 acc = make_float4(0.f, 0.f, 0.f, 0.f);
    float m = -INFINITY, lsum = 0.f;

    int e0 = rowptr[n], e1 = rowptr[n + 1];
    if (e0 < e1) {
        int sID = srcid[e0];
        ushort4 kcur = *(const ushort4*)(k + (size_t)sID * 128 + l * 4);
        ushort4 vcur = *(const ushort4*)(v + (size_t)sID * 128 + l * 4);
        for (int e = e0; e < e1; ++e) {
            int nextS = (e + 1 < e1) ? srcid[e + 1] : sID;
            ushort4 kn = *(const ushort4*)(k + (size_t)nextS * 128 + l * 4);
            ushort4 vn = *(const ushort4*)(v + (size_t)nextS * 128 + l * 4);
            float p = qv.x * b2f(kcur.x) + qv.y * b2f(kcur.y)
                    + qv.z * b2f(kcur.z) + qv.w * b2f(kcur.w);
            p += __shfl_xor(p, 1, 8);
            p += __shfl_xor(p, 2, 8);
            p += __shfl_xor(p, 4, 8);
            float logit = p * scale;
            float mn = fmaxf(m, logit);
            float ex = __expf(logit - mn);
            float sc = __expf(m - mn);
            lsum = lsum * sc + ex;
            acc.x = acc.x * sc + ex * b2f(vcur.x);
            acc.y = acc.y * sc + ex * b2f(vcur.y);
            acc.z = acc.z * sc + ex * b2f(vcur.z);
            acc.w = acc.w * sc + ex * b2f(vcur.w);
            m = mn;
            kcur = kn; vcur = vn;
        }
    }

    float inv = 0.25f / fmaxf(lsum, 1e-16f);
    float rx = acc.x * inv, ry = acc.y * inv, rz = acc.z * inv, rw = acc.w * inv;
    rx += __shfl_xor(rx, 8, 32);  rx += __shfl_xor(rx, 16, 32);
    ry += __shfl_xor(ry, 8, 32);  ry += __shfl_xor(ry, 16, 32);
    rz += __shfl_xor(rz, 8, 32);  rz += __shfl_xor(rz, 16, 32);
    rw += __shfl_xor(rw, 8, 32);  rw += __shfl_xor(rw, 16, 32);

    if (l < 8) {
        const float* skp = sk + (size_t)n * 32 + s * 4;
        float o0 = fmaxf(rx + skp[0], 0.f), o1 = fmaxf(ry + skp[1], 0.f);
        float o2 = fmaxf(rz + skp[2], 0.f), o3 = fmaxf(rw + skp[3], 0.f);
        if (mode == 0) {
            *(float4*)(outF + (size_t)n * 32 + s * 4) = make_float4(o0, o1, o2, o3);
        } else {
            ushort4 h, L;
            h.x = f2b(o0); L.x = f2b(o0 - b2f(h.x));
            h.y = f2b(o1); L.y = f2b(o1 - b2f(h.y));
            h.z = f2b(o2); L.z = f2b(o2 - b2f(h.z));
            h.w = f2b(o3); L.w = f2b(o3 - b2f(h.w));
            *(ushort4*)(outHi + (size_t)n * 32 + s * 4) = h;
            *(ushort4*)(outLo + (size_t)n * 32 + s * 4) = L;
        }
    }
}

// ---------------- global mean pool (batch is sorted) ----------------

__global__ __launch_bounds__(256) void pool_k(const float* __restrict__ h, const int* __restrict__ batch,
                                              float* __restrict__ out, int N)
{
    int g = blockIdx.x;
    int t = threadIdx.x;
    int lo = 0, hi = N;
    while (lo < hi) { int mid = (lo + hi) >> 1; if (batch[mid] < g) lo = mid + 1; else hi = mid; }
    int start = lo;
    lo = 0; hi = N;
    while (lo < hi) { int mid = (lo + hi) >> 1; if (batch[mid] < g + 1) lo = mid + 1; else hi = mid; }
    int end = lo;
    int c = t & 31, r0 = t >> 5;
    float s = 0.f;
    for (int r = start + r0; r < end; r += 8) s += h[(size_t)r * 32 + c];
    __shared__ float sh[256];
    sh[t] = s;
    __syncthreads();
    if (t < 32) {
        float tot = sh[t] + sh[t + 32] + sh[t + 64] + sh[t + 96]
                  + sh[t + 128] + sh[t + 160] + sh[t + 192] + sh[t + 224];
        float cnt = (float)(end - start);
        out[(size_t)g * 32 + t] = tot / fmaxf(cnt, 1.f);
    }
}

// ---------------- launch ----------------

extern "C" void kernel_launch(void* const* d_in, const int* in_sizes, int n_in,
                              void* d_out, int out_size, void* d_ws, size_t ws_size,
                              hipStream_t stream) {
    const float* x   = (const float*)d_in[0];
    const int* ei    = (const int*)d_in[1];
    const int* batch = (const int*)d_in[2];
    const float *Wq1 = (const float*)d_in[3],  *bq1 = (const float*)d_in[4];
    const float *Wk1 = (const float*)d_in[5],  *bk1 = (const float*)d_in[6];
    const float *Wv1 = (const float*)d_in[7],  *bv1 = (const float*)d_in[8];
    const float *Ws1 = (const float*)d_in[9],  *bs1 = (const float*)d_in[10];
    const float *Wq2 = (const float*)d_in[11], *bq2 = (const float*)d_in[12];
    const float *Wk2 = (const float*)d_in[13], *bk2 = (const float*)d_in[14];
    const float *Wv2 = (const float*)d_in[15], *bv2 = (const float*)d_in[16];
    const float *Ws2 = (const float*)d_in[17], *bs2 = (const float*)d_in[18];
    float* out = (float*)d_out;

    int N = in_sizes[0] / 128;
    int E = in_sizes[1] / 2;
    const int* src = ei;
    const int* dst = ei + E;

    char* ws = (char*)d_ws;
    size_t off = 0;
    auto alloc = [&](size_t bytes) -> void* {
        void* p = ws + off;
        off += (bytes + 255) & ~(size_t)255;
        return p;
    };
    int* deg      = (int*)alloc((size_t)N * 4);
    int* cnt      = (int*)alloc((size_t)N * 4);
    int* rowptr   = (int*)alloc(((size_t)N + 1) * 4);
    int* partials = (int*)alloc(4096);
    int* srcid    = (int*)alloc((size_t)E * 4);
    unsigned* fhi1 = (unsigned*)alloc(26 * 4 * 64 * 4 * 4);
    unsigned* flo1 = (unsigned*)alloc(26 * 4 * 64 * 4 * 4);
    unsigned* fhi2 = (unsigned*)alloc(26 * 1 * 64 * 4 * 4);
    unsigned* flo2 = (unsigned*)alloc(26 * 1 * 64 * 4 * 4);
    unsigned short* Xhi = (unsigned short*)alloc((size_t)N * 128 * 2);
    unsigned short* Xlo = (unsigned short*)alloc((size_t)N * 128 * 2);
    float* q            = (float*)alloc((size_t)N * 128 * 4);
    unsigned short* kb  = (unsigned short*)alloc((size_t)N * 128 * 2);
    unsigned short* vb  = (unsigned short*)alloc((size_t)N * 128 * 2);
    float* sk     = (float*)alloc((size_t)N * 32 * 4);
    unsigned short* h1hi = (unsigned short*)alloc((size_t)N * 32 * 2);
    unsigned short* h1lo = (unsigned short*)alloc((size_t)N * 32 * 2);
    float* h2     = (float*)alloc((size_t)N * 32 * 4);

    hipMemsetAsync(deg, 0, (size_t)N * 4, stream);
    hipMemsetAsync(cnt, 0, (size_t)N * 4, stream);

    int nch = (N + 1023) / 1024;
    hist_k<<<(E + 255) / 256, 256, 0, stream>>>(dst, deg, E);
    scanA_k<<<nch, 256, 0, stream>>>(deg, rowptr, partials, N);
    scanB_k<<<1, 64, 0, stream>>>(partials, nch);
    addoff_k<<<nch, 256, 0, stream>>>(rowptr, partials, N, nch);
    scatter_k<<<(E + 255) / 256, 256, 0, stream>>>(src, dst, rowptr, cnt, srcid, E);

    wprep_k<<<(26 * 4 * 64 * 4 + 255) / 256, 256, 0, stream>>>(Wq1, Wk1, Wv1, Ws1, 4, fhi1, flo1);
    wprep_k<<<(26 * 1 * 64 * 4 + 255) / 256, 256, 0, stream>>>(Wq2, Wk2, Wv2, Ws2, 1, fhi2, flo2);
    cvt_k<<<2048, 256, 0, stream>>>(x, Xhi, Xlo, (long)N * 32);

    dim3 gq((N + 127) / 128, 4);
    qkvs_mfma<4, 2><<<gq, 256, 0, stream>>>(Xhi, Xlo, 128, N, fhi1, flo1,
        bq1, bk1, bv1, bs1, q, kb, vb, sk);
    attn_k<<<(N + 7) / 8, 256, 0, stream>>>(q, kb, vb, sk, rowptr, srcid,
        nullptr, h1hi, h1lo, 1, N);
    qkvs_mfma<1, 1><<<gq, 256, 0, stream>>>(h1hi, h1lo, 32, N, fhi2, flo2,
        bq2, bk2, bv2, bs2, q, kb, vb, sk);
    attn_k<<<(N + 7) / 8, 256, 0, stream>>>(q, kb, vb, sk, rowptr, srcid,
        h2, nullptr, nullptr, 0, N);
    pool_k<<<512, 256, 0, stream>>>(h2, batch, out, N);
}